// Round 7
// baseline (125.365 us; speedup 1.0000x reference)
//
#include <hip/hip_runtime.h>
#include <hip/hip_bf16.h>

#define D_IN   128
#define D_OUT  64
#define CAP    64          // per-node bucket capacity; overflow exact via facc
#define MAX_USHORT_NODES 65536
#define BIN_SHIFT 8        // 256 node ids per bin
#define MAX_BINS  256
#define BIN_CAP   8192     // scratch slots per bin (expected ~4082; exact via ovfA)
#define P1_BLOCKS 256
#define FAT_THREADS 512
#define SPLIT 4            // bin_gather blocks per bin (64 nodes each)
#define SPLIT_SHIFT 2

using frag_ab = __attribute__((ext_vector_type(8))) short;  // 8 bf16
using frag_cd = __attribute__((ext_vector_type(4))) float;  // 4 fp32

static __device__ __forceinline__ short f2bf(float f) {
    union { float f; unsigned u; } v; v.f = f;
    unsigned r = v.u + 0x7FFFu + ((v.u >> 16) & 1u);   // RNE truncate to bf16
    return (short)(r >> 16);
}
static __device__ __forceinline__ float bflo(unsigned w) {
    union { unsigned u; float f; } v; v.u = w << 16; return v.f;
}
static __device__ __forceinline__ float bfhi(unsigned w) {
    union { unsigned u; float f; } v; v.u = w & 0xFFFF0000u; return v.f;
}

// exact streaming accumulate of h-row c into facc row r6 (overflow path;
// zero-cost when no node exceeds CAP)
static __device__ __forceinline__ void facc_accum(float* facc,
                                                  const uint2* __restrict__ h64,
                                                  int r6, int c) {
    const uint2* hr = h64 + (size_t)c * 16;
#pragma unroll 4
    for (int t = 0; t < 16; ++t) {
        const uint2 wv = hr[t];
        atomicAdd(&facc[(r6 << 6) + t * 4 + 0], bflo(wv.x));
        atomicAdd(&facc[(r6 << 6) + t * 4 + 1], bfhi(wv.x));
        atomicAdd(&facc[(r6 << 6) + t * 4 + 2], bflo(wv.y));
        atomicAdd(&facc[(r6 << 6) + t * 4 + 3], bfhi(wv.y));
    }
}

// ---------------------------------------------------------------------------
// Fat kernel (identical to round-6): blocks [0, P1_BLOCKS) run binpass1
// (per-block LDS histogram -> one global atomic per (block,bin) -> packed
// scatter into bin scratch); blocks [P1_BLOCKS, ...) run the MFMA projection.
// Record pack: (r & 255) | c << 8.
// ---------------------------------------------------------------------------
__global__ __launch_bounds__(FAT_THREADS)
void proj_bin1_kernel(const float* __restrict__ x,
                      const float* __restrict__ W,
                      const float* __restrict__ bvec,
                      unsigned short* __restrict__ h,
                      const int* __restrict__ row, const int* __restrict__ col,
                      unsigned* __restrict__ scratch, int* __restrict__ cursor,
                      int* __restrict__ ovfA_cnt, unsigned* __restrict__ ovfA_list,
                      int ovfA_cap, int n_nodes, int n_edges, int n_bins) {
    __shared__ int hist[MAX_BINS];
    __shared__ int base[MAX_BINS];

    if ((int)blockIdx.x < P1_BLOCKS) {
        // ---- binpass1 ----
        const int per = (n_edges + P1_BLOCKS - 1) / P1_BLOCKS;
        const int e0 = (int)blockIdx.x * per;
        const int e1 = min(e0 + per, n_edges);

        for (int i = threadIdx.x; i < n_bins; i += FAT_THREADS) hist[i] = 0;
        __syncthreads();
        for (int e = e0 + (int)threadIdx.x; e < e1; e += FAT_THREADS)
            atomicAdd(&hist[row[e] >> BIN_SHIFT], 1);
        __syncthreads();
        for (int i = threadIdx.x; i < n_bins; i += FAT_THREADS) {
            const int hcnt = hist[i];
            base[i] = hcnt > 0 ? atomicAdd(&cursor[i * 16], hcnt) : 0;
            hist[i] = 0;
        }
        __syncthreads();
        for (int e = e0 + (int)threadIdx.x; e < e1; e += FAT_THREADS) {
            const int r = row[e];
            const int c = col[e];
            const int bn = r >> BIN_SHIFT;
            const int loc = atomicAdd(&hist[bn], 1);
            const int off = base[bn] + loc;
            if (off < BIN_CAP) {
                scratch[(size_t)bn * BIN_CAP + off] =
                    (unsigned)(r & 255) | ((unsigned)c << 8);
            } else {
                const int k = atomicAdd(ovfA_cnt, 1);
                if (k < ovfA_cap) ovfA_list[k] = (unsigned)r | ((unsigned)c << 16);
            }
        }
        return;
    }

    // ---- projection: wave = 16-node tile, grid-stride over proj blocks ----
    const int lane = (int)threadIdx.x & 63;
    const int wid  = ((int)blockIdx.x - P1_BLOCKS) * (FAT_THREADS >> 6)
                   + ((int)threadIdx.x >> 6);
    const int nwaves = ((int)gridDim.x - P1_BLOCKS) * (FAT_THREADS >> 6);
    const int m    = lane & 15;
    const int quad = lane >> 4;

    frag_ab Bf[4][4];
#pragma unroll
    for (int kk = 0; kk < 4; ++kk) {
#pragma unroll
        for (int nt = 0; nt < 4; ++nt) {
            const float* wp = W + (size_t)(nt * 16 + m) * D_IN + kk * 32 + quad * 8;
            const float4 w0 = *(const float4*)wp;
            const float4 w1 = *(const float4*)(wp + 4);
            frag_ab f;
            f[0] = f2bf(w0.x); f[1] = f2bf(w0.y); f[2] = f2bf(w0.z); f[3] = f2bf(w0.w);
            f[4] = f2bf(w1.x); f[5] = f2bf(w1.y); f[6] = f2bf(w1.z); f[7] = f2bf(w1.w);
            Bf[kk][nt] = f;
        }
    }
    float bb[4];
#pragma unroll
    for (int nt = 0; nt < 4; ++nt) bb[nt] = bvec[nt * 16 + m];

    const int ntiles = (n_nodes + 15) / 16;
    for (int tile = wid; tile < ntiles; tile += nwaves) {
        const int node_base = tile * 16;
        int arow = node_base + m;
        if (arow > n_nodes - 1) arow = n_nodes - 1;

        float4 xv[8];
        const float* xr = x + (size_t)arow * D_IN + quad * 8;
#pragma unroll
        for (int kk = 0; kk < 4; ++kk) {
            xv[2 * kk]     = *(const float4*)(xr + kk * 32);
            xv[2 * kk + 1] = *(const float4*)(xr + kk * 32 + 4);
        }

        frag_cd acc[4];
#pragma unroll
        for (int nt = 0; nt < 4; ++nt) {
            acc[nt][0] = bb[nt]; acc[nt][1] = bb[nt];
            acc[nt][2] = bb[nt]; acc[nt][3] = bb[nt];
        }
#pragma unroll
        for (int kk = 0; kk < 4; ++kk) {
            const float4 x0 = xv[2 * kk], x1 = xv[2 * kk + 1];
            frag_ab A;
            A[0] = f2bf(x0.x); A[1] = f2bf(x0.y); A[2] = f2bf(x0.z); A[3] = f2bf(x0.w);
            A[4] = f2bf(x1.x); A[5] = f2bf(x1.y); A[6] = f2bf(x1.z); A[7] = f2bf(x1.w);
#pragma unroll
            for (int nt = 0; nt < 4; ++nt)
                acc[nt] = __builtin_amdgcn_mfma_f32_16x16x32_bf16(A, Bf[kk][nt],
                                                                  acc[nt], 0, 0, 0);
        }
#pragma unroll
        for (int nt = 0; nt < 4; ++nt) {
#pragma unroll
            for (int r = 0; r < 4; ++r) {
                const int node = node_base + quad * 4 + r;
                if (node < n_nodes)
                    h[(size_t)node * D_OUT + nt * 16 + m] =
                        (unsigned short)f2bf(acc[nt][r]);
            }
        }
    }
}

// ---------------------------------------------------------------------------
// Fused bucket-build + gather, exact (no downstream overflow kernel).
// Block = (bin, slice of 64 nodes). Build phase identical to round 6.
// Gather phase: wave processes NODE PAIRS (r6, r6+32) with independent
// accumulators -> 8 h-row loads in flight per step, halving the exposed
// latencies per wave (8 -> 4). Quarter-wave per bucket entry, uint2 loads,
// shfl_xor reduce, facc fold, fused mean. Block owns its 64 out rows.
// ---------------------------------------------------------------------------
__global__ __launch_bounds__(FAT_THREADS)
void bin_gather_kernel(const unsigned* __restrict__ scratch,
                       const int* __restrict__ cursor,
                       const uint2* __restrict__ h64,
                       int* __restrict__ deg,
                       const unsigned* __restrict__ ovfA_list,
                       const int* __restrict__ ovfA_cnt, int ovfA_cap,
                       float* __restrict__ out, int n_nodes) {
    __shared__ int ldeg[64];
    __shared__ unsigned short lbuck[64 * CAP];   // 8 KB
    __shared__ float facc[64 * D_OUT];           // 16 KB overflow accumulator
    const int g     = (int)blockIdx.x;
    const int bin   = g >> SPLIT_SHIFT;
    const int slice = g & (SPLIT - 1);
    const int node0 = (bin << BIN_SHIFT) + (slice << 6);
    const int tid   = (int)threadIdx.x;

    int cnt = cursor[bin * 16]; if (cnt > BIN_CAP) cnt = BIN_CAP;

    if (tid < 64) ldeg[tid] = 0;
    for (int i = tid; i < 64 * D_OUT; i += FAT_THREADS) facc[i] = 0.f;
    __syncthreads();

    // scan the bin's records, keep rows in [slice*64, slice*64+64)
    for (int i = tid; i < cnt; i += FAT_THREADS) {
        const unsigned rec = scratch[(size_t)bin * BIN_CAP + i];
        const int rl = (int)(rec & 255u);
        if ((rl >> 6) == slice) {
            const int r6 = rl & 63;
            const int s = atomicAdd(&ldeg[r6], 1);
            if (s < CAP) lbuck[(r6 << 6) + s] = (unsigned short)(rec >> 8);
            else         facc_accum(facc, h64, r6, (int)(rec >> 8));
        }
    }
    // pass1-overflow edges: same path (deg + contribution), fast path = 0 work
    int cA = *ovfA_cnt; if (cA > ovfA_cap) cA = ovfA_cap;
    if (cA > 0) {
        const int gslice = node0 >> 6;
        for (int i = tid; i < cA; i += FAT_THREADS) {
            const unsigned rec = ovfA_list[i];
            const int r = (int)(rec & 0xFFFFu);
            if ((r >> 6) == gslice) {
                const int r6 = r & 63;
                const int c = (int)(rec >> 16);
                const int s = atomicAdd(&ldeg[r6], 1);
                if (s < CAP) lbuck[(r6 << 6) + s] = (unsigned short)c;
                else         facc_accum(facc, h64, r6, c);
            }
        }
    }
    __syncthreads();

    if (tid < 64 && node0 + tid < n_nodes) deg[node0 + tid] = ldeg[tid];

    // gather: node pairs (rA, rB = rA+32) with independent accumulators
    const int lane = tid & 63;
    const int q = lane >> 4;
    const int j = lane & 15;
    const int w = tid >> 6;   // wave 0..7

    for (int pr = w; pr < 32; pr += 8) {
        const int rA = pr, rB = pr + 32;
        const int nodeA = node0 + rA, nodeB = node0 + rB;
        const int dA = ldeg[rA], dB = ldeg[rB];
        const int dcA = dA < CAP ? dA : CAP;
        const int dcB = dB < CAP ? dB : CAP;
        const int dcM = dcA > dcB ? dcA : dcB;
        const int ngr = (dcM + 3) >> 2;
        const unsigned short* browA = &lbuck[rA << 6];
        const unsigned short* browB = &lbuck[rB << 6];

        float pA0 = 0.f, pA1 = 0.f, pA2 = 0.f, pA3 = 0.f;
        float qA0 = 0.f, qA1 = 0.f, qA2 = 0.f, qA3 = 0.f;
        float pB0 = 0.f, pB1 = 0.f, pB2 = 0.f, pB3 = 0.f;
        float qB0 = 0.f, qB1 = 0.f, qB2 = 0.f, qB3 = 0.f;

        for (int g2 = 0; g2 < ngr; g2 += 4) {   // 8 loads in flight
            const int e0 = 4 * g2 + q;
            const int e1 = e0 + 4, e2 = e0 + 8, e3 = e0 + 12;
            // indices (LDS broadcast per quarter); entries beyond dc read
            // uninitialized lbuck -> index < 65536 -> address stays inside
            // the workspace (safe), value masked to 0 below.
            const int iA0 = (int)browA[e0];
            const int iA1 = (int)browA[e1];
            const int iA2 = (int)browA[e2];
            const int iA3 = (int)browA[e3];
            const int iB0 = (int)browB[e0];
            const int iB1 = (int)browB[e1];
            const int iB2 = (int)browB[e2];
            const int iB3 = (int)browB[e3];
            uint2 wA0 = h64[(size_t)iA0 * 16 + j];
            uint2 wA1 = h64[(size_t)iA1 * 16 + j];
            uint2 wA2 = h64[(size_t)iA2 * 16 + j];
            uint2 wA3 = h64[(size_t)iA3 * 16 + j];
            uint2 wB0 = h64[(size_t)iB0 * 16 + j];
            uint2 wB1 = h64[(size_t)iB1 * 16 + j];
            uint2 wB2 = h64[(size_t)iB2 * 16 + j];
            uint2 wB3 = h64[(size_t)iB3 * 16 + j];
            if (e0 >= dcA) { wA0.x = 0u; wA0.y = 0u; }
            if (e1 >= dcA) { wA1.x = 0u; wA1.y = 0u; }
            if (e2 >= dcA) { wA2.x = 0u; wA2.y = 0u; }
            if (e3 >= dcA) { wA3.x = 0u; wA3.y = 0u; }
            if (e0 >= dcB) { wB0.x = 0u; wB0.y = 0u; }
            if (e1 >= dcB) { wB1.x = 0u; wB1.y = 0u; }
            if (e2 >= dcB) { wB2.x = 0u; wB2.y = 0u; }
            if (e3 >= dcB) { wB3.x = 0u; wB3.y = 0u; }
            pA0 += bflo(wA0.x); pA1 += bfhi(wA0.x); pA2 += bflo(wA0.y); pA3 += bfhi(wA0.y);
            qA0 += bflo(wA1.x); qA1 += bfhi(wA1.x); qA2 += bflo(wA1.y); qA3 += bfhi(wA1.y);
            pA0 += bflo(wA2.x); pA1 += bfhi(wA2.x); pA2 += bflo(wA2.y); pA3 += bfhi(wA2.y);
            qA0 += bflo(wA3.x); qA1 += bfhi(wA3.x); qA2 += bflo(wA3.y); qA3 += bfhi(wA3.y);
            pB0 += bflo(wB0.x); pB1 += bfhi(wB0.x); pB2 += bflo(wB0.y); pB3 += bfhi(wB0.y);
            qB0 += bflo(wB1.x); qB1 += bfhi(wB1.x); qB2 += bflo(wB1.y); qB3 += bfhi(wB1.y);
            pB0 += bflo(wB2.x); pB1 += bfhi(wB2.x); pB2 += bflo(wB2.y); pB3 += bfhi(wB2.y);
            qB0 += bflo(wB3.x); qB1 += bfhi(wB3.x); qB2 += bflo(wB3.y); qB3 += bfhi(wB3.y);
        }
        pA0 += qA0; pA1 += qA1; pA2 += qA2; pA3 += qA3;
        pB0 += qB0; pB1 += qB1; pB2 += qB2; pB3 += qB3;
        pA0 += __shfl_xor(pA0, 16); pA0 += __shfl_xor(pA0, 32);
        pA1 += __shfl_xor(pA1, 16); pA1 += __shfl_xor(pA1, 32);
        pA2 += __shfl_xor(pA2, 16); pA2 += __shfl_xor(pA2, 32);
        pA3 += __shfl_xor(pA3, 16); pA3 += __shfl_xor(pA3, 32);
        pB0 += __shfl_xor(pB0, 16); pB0 += __shfl_xor(pB0, 32);
        pB1 += __shfl_xor(pB1, 16); pB1 += __shfl_xor(pB1, 32);
        pB2 += __shfl_xor(pB2, 16); pB2 += __shfl_xor(pB2, 32);
        pB3 += __shfl_xor(pB3, 16); pB3 += __shfl_xor(pB3, 32);
        if (q == 0) {
            if (nodeA < n_nodes) {
                const float* fa = &facc[(rA << 6) + j * 4];
                const float inv = 1.0f / fmaxf((float)dA, 1.0f);
                float4 o;
                o.x = (pA0 + fa[0]) * inv; o.y = (pA1 + fa[1]) * inv;
                o.z = (pA2 + fa[2]) * inv; o.w = (pA3 + fa[3]) * inv;
                *(float4*)(out + (size_t)nodeA * D_OUT + j * 4) = o;
            }
            if (nodeB < n_nodes) {
                const float* fb = &facc[(rB << 6) + j * 4];
                const float inv = 1.0f / fmaxf((float)dB, 1.0f);
                float4 o;
                o.x = (pB0 + fb[0]) * inv; o.y = (pB1 + fb[1]) * inv;
                o.z = (pB2 + fb[2]) * inv; o.w = (pB3 + fb[3]) * inv;
                *(float4*)(out + (size_t)nodeB * D_OUT + j * 4) = o;
            }
        }
    }
}

// ---------------------------------------------------------------------------
// Last-resort path (ws too small or n_nodes > 65536): fp32 h + atomic scatter.
// ---------------------------------------------------------------------------
__global__ void proj_only_kernel(const float* __restrict__ x,
                                 const float* __restrict__ W,
                                 const float* __restrict__ bvec,
                                 float* __restrict__ h, int n_nodes) {
    const int lane = (int)threadIdx.x & 63;
    const int wave = (int)((blockIdx.x * blockDim.x + threadIdx.x) >> 6);
    const int nwaves = (int)((gridDim.x * blockDim.x) >> 6);
    const float bias = bvec[lane];
    for (int node = wave; node < n_nodes; node += nwaves) {
        const float* xr = &x[(size_t)node * D_IN];
        float acc = bias;
#pragma unroll
        for (int k = 0; k < D_IN; ++k) acc += xr[k] * W[lane * D_IN + k];
        h[(size_t)node * D_OUT + lane] = acc;
    }
}

__global__ void scatter_kernel(const float* __restrict__ h,
                               const int* __restrict__ row,
                               const int* __restrict__ col,
                               float* __restrict__ out,
                               int* __restrict__ deg,
                               long long n_tasks) {
    long long t = (long long)blockIdx.x * blockDim.x + threadIdx.x;
    const long long stride = (long long)gridDim.x * blockDim.x;
    for (; t < n_tasks; t += stride) {
        const int e = (int)(t >> 6);
        const int c = (int)(t & 63);
        atomicAdd(&out[(size_t)row[e] * D_OUT + c], h[(size_t)col[e] * D_OUT + c]);
        if (c == 0) atomicAdd(&deg[row[e]], 1);
    }
}

__global__ void div_kernel(float* __restrict__ out,
                           const int* __restrict__ deg, int n_total) {
    int t = blockIdx.x * blockDim.x + threadIdx.x;
    if (t < n_total) {
        out[t] *= 1.0f / fmaxf((float)deg[t >> 6], 1.0f);
    }
}

extern "C" void kernel_launch(void* const* d_in, const int* in_sizes, int n_in,
                              void* d_out, int out_size, void* d_ws, size_t ws_size,
                              hipStream_t stream) {
    const float* x   = (const float*)d_in[0];
    const float* W   = (const float*)d_in[1];
    const float* b   = (const float*)d_in[2];
    const int*   row = (const int*)d_in[3];
    const int*   col = (const int*)d_in[4];
    float* out = (float*)d_out;

    const int n_nodes = in_sizes[0] / D_IN;
    const int n_edges = in_sizes[3];
    const int n_bins  = (n_nodes + 255) >> BIN_SHIFT;

    // Workspace: h(bf16) | deg | [ovfA_cnt pad 256B] | cursor(padded)
    //            | ovfA_list | scratch
    char* p = (char*)d_ws;
    unsigned short* h = (unsigned short*)p;
    p += (size_t)n_nodes * D_OUT * sizeof(unsigned short);
    int* deg = (int*)p;            p += (size_t)n_nodes * sizeof(int);
    int* ovf_cnts = (int*)p;       p += 256;                       // [0]=A
    int* cursor = (int*)p;         p += (size_t)MAX_BINS * 16 * sizeof(int);
    unsigned* ovfA_list = (unsigned*)p;  p += (size_t)n_edges * sizeof(unsigned);
    unsigned* scratch = (unsigned*)p;
    p += (size_t)n_bins * BIN_CAP * sizeof(unsigned);
    const size_t needed = (size_t)(p - (char*)d_ws);

    if (ws_size >= needed && n_nodes <= MAX_USHORT_NODES) {
        // zero: ovfA counter + padded cursor (contiguous)
        hipMemsetAsync(ovf_cnts, 0, 256 + (size_t)MAX_BINS * 16 * sizeof(int),
                       stream);

        // 1) projection || binpass1 (independent; complementary pipes)
        const int ntiles = (n_nodes + 15) / 16;
        int proj_blocks = (ntiles + 15) / 16;     // 8 waves/block, 2 tiles/wave
        if (proj_blocks < 1) proj_blocks = 1;
        proj_bin1_kernel<<<P1_BLOCKS + proj_blocks, FAT_THREADS, 0, stream>>>(
            x, W, b, h, row, col, scratch, cursor, &ovf_cnts[0], ovfA_list,
            n_edges, n_nodes, n_edges, n_bins);

        // 2) fused bucket-build + gather, exact (no downstream kernel)
        bin_gather_kernel<<<n_bins * SPLIT, FAT_THREADS, 0, stream>>>(
            scratch, cursor, (const uint2*)h, deg, ovfA_list, &ovf_cnts[0],
            n_edges, out, n_nodes);
    } else {
        // last resort: fp32 h + atomic scatter
        float* hf = (float*)d_ws;
        int* degf = (int*)((char*)d_ws + (size_t)n_nodes * D_OUT * sizeof(float));
        hipMemsetAsync(out, 0, (size_t)out_size * sizeof(float), stream);
        hipMemsetAsync(degf, 0, (size_t)n_nodes * sizeof(int), stream);
        proj_only_kernel<<<1024, 256, 0, stream>>>(x, W, b, hf, n_nodes);
        const long long n_tasks = (long long)n_edges * D_OUT;
        scatter_kernel<<<16384, 256, 0, stream>>>(hf, row, col, out, degf, n_tasks);
        const int n_total = n_nodes * D_OUT;
        div_kernel<<<(n_total + 255) / 256, 256, 0, stream>>>(out, degf, n_total);
    }
}

// Round 8
// 122.988 us; speedup vs baseline: 1.0193x; 1.0193x over previous
//
#include <hip/hip_runtime.h>
#include <hip/hip_bf16.h>

#define D_IN   128
#define D_OUT  64
#define CAP    64          // per-node bucket capacity; overflow exact via facc
#define MAX_USHORT_NODES 65536
#define BIN_SHIFT 8        // 256 node ids per bin
#define MAX_BINS  256
#define BIN_CAP   8192     // scratch slots per bin (expected ~4082; exact via ovfA)
#define P1_BLOCKS 256
#define FAT_THREADS 512
#define SPLIT 4            // bin_gather blocks per bin (64 nodes each)
#define SPLIT_SHIFT 2

using frag_ab = __attribute__((ext_vector_type(8))) short;  // 8 bf16
using frag_cd = __attribute__((ext_vector_type(4))) float;  // 4 fp32

static __device__ __forceinline__ short f2bf(float f) {
    union { float f; unsigned u; } v; v.f = f;
    unsigned r = v.u + 0x7FFFu + ((v.u >> 16) & 1u);   // RNE truncate to bf16
    return (short)(r >> 16);
}
static __device__ __forceinline__ float bflo(unsigned w) {
    union { unsigned u; float f; } v; v.u = w << 16; return v.f;
}
static __device__ __forceinline__ float bfhi(unsigned w) {
    union { unsigned u; float f; } v; v.u = w & 0xFFFF0000u; return v.f;
}

// exact streaming accumulate of h-row c into facc row r6 (overflow path;
// zero-cost when no node exceeds CAP)
static __device__ __forceinline__ void facc_accum(float* facc,
                                                  const uint2* __restrict__ h64,
                                                  int r6, int c) {
    const uint2* hr = h64 + (size_t)c * 16;
#pragma unroll 4
    for (int t = 0; t < 16; ++t) {
        const uint2 wv = hr[t];
        atomicAdd(&facc[(r6 << 6) + t * 4 + 0], bflo(wv.x));
        atomicAdd(&facc[(r6 << 6) + t * 4 + 1], bfhi(wv.x));
        atomicAdd(&facc[(r6 << 6) + t * 4 + 2], bflo(wv.y));
        atomicAdd(&facc[(r6 << 6) + t * 4 + 3], bfhi(wv.y));
    }
}

// ---------------------------------------------------------------------------
// Fat kernel: blocks [0, P1_BLOCKS) run binpass1 (per-block LDS histogram ->
// one global atomic per (block,bin) -> packed scatter into bin scratch);
// blocks [P1_BLOCKS, ...) run the MFMA projection.
// Record pack: (r & 255) | c << 8.
// ---------------------------------------------------------------------------
__global__ __launch_bounds__(FAT_THREADS)
void proj_bin1_kernel(const float* __restrict__ x,
                      const float* __restrict__ W,
                      const float* __restrict__ bvec,
                      unsigned short* __restrict__ h,
                      const int* __restrict__ row, const int* __restrict__ col,
                      unsigned* __restrict__ scratch, int* __restrict__ cursor,
                      int* __restrict__ ovfA_cnt, unsigned* __restrict__ ovfA_list,
                      int ovfA_cap, int n_nodes, int n_edges, int n_bins) {
    __shared__ int hist[MAX_BINS];
    __shared__ int base[MAX_BINS];

    if ((int)blockIdx.x < P1_BLOCKS) {
        // ---- binpass1 ----
        const int per = (n_edges + P1_BLOCKS - 1) / P1_BLOCKS;
        const int e0 = (int)blockIdx.x * per;
        const int e1 = min(e0 + per, n_edges);

        for (int i = threadIdx.x; i < n_bins; i += FAT_THREADS) hist[i] = 0;
        __syncthreads();
        for (int e = e0 + (int)threadIdx.x; e < e1; e += FAT_THREADS)
            atomicAdd(&hist[row[e] >> BIN_SHIFT], 1);
        __syncthreads();
        for (int i = threadIdx.x; i < n_bins; i += FAT_THREADS) {
            const int hcnt = hist[i];
            base[i] = hcnt > 0 ? atomicAdd(&cursor[i * 16], hcnt) : 0;
            hist[i] = 0;
        }
        __syncthreads();
        for (int e = e0 + (int)threadIdx.x; e < e1; e += FAT_THREADS) {
            const int r = row[e];
            const int c = col[e];
            const int bn = r >> BIN_SHIFT;
            const int loc = atomicAdd(&hist[bn], 1);
            const int off = base[bn] + loc;
            if (off < BIN_CAP) {
                scratch[(size_t)bn * BIN_CAP + off] =
                    (unsigned)(r & 255) | ((unsigned)c << 8);
            } else {
                const int k = atomicAdd(ovfA_cnt, 1);
                if (k < ovfA_cap) ovfA_list[k] = (unsigned)r | ((unsigned)c << 16);
            }
        }
        return;
    }

    // ---- projection: wave = 16-node tile, grid-stride over proj blocks ----
    const int lane = (int)threadIdx.x & 63;
    const int wid  = ((int)blockIdx.x - P1_BLOCKS) * (FAT_THREADS >> 6)
                   + ((int)threadIdx.x >> 6);
    const int nwaves = ((int)gridDim.x - P1_BLOCKS) * (FAT_THREADS >> 6);
    const int m    = lane & 15;
    const int quad = lane >> 4;

    frag_ab Bf[4][4];
#pragma unroll
    for (int kk = 0; kk < 4; ++kk) {
#pragma unroll
        for (int nt = 0; nt < 4; ++nt) {
            const float* wp = W + (size_t)(nt * 16 + m) * D_IN + kk * 32 + quad * 8;
            const float4 w0 = *(const float4*)wp;
            const float4 w1 = *(const float4*)(wp + 4);
            frag_ab f;
            f[0] = f2bf(w0.x); f[1] = f2bf(w0.y); f[2] = f2bf(w0.z); f[3] = f2bf(w0.w);
            f[4] = f2bf(w1.x); f[5] = f2bf(w1.y); f[6] = f2bf(w1.z); f[7] = f2bf(w1.w);
            Bf[kk][nt] = f;
        }
    }
    float bb[4];
#pragma unroll
    for (int nt = 0; nt < 4; ++nt) bb[nt] = bvec[nt * 16 + m];

    const int ntiles = (n_nodes + 15) / 16;
    for (int tile = wid; tile < ntiles; tile += nwaves) {
        const int node_base = tile * 16;
        int arow = node_base + m;
        if (arow > n_nodes - 1) arow = n_nodes - 1;

        float4 xv[8];
        const float* xr = x + (size_t)arow * D_IN + quad * 8;
#pragma unroll
        for (int kk = 0; kk < 4; ++kk) {
            xv[2 * kk]     = *(const float4*)(xr + kk * 32);
            xv[2 * kk + 1] = *(const float4*)(xr + kk * 32 + 4);
        }

        frag_cd acc[4];
#pragma unroll
        for (int nt = 0; nt < 4; ++nt) {
            acc[nt][0] = bb[nt]; acc[nt][1] = bb[nt];
            acc[nt][2] = bb[nt]; acc[nt][3] = bb[nt];
        }
#pragma unroll
        for (int kk = 0; kk < 4; ++kk) {
            const float4 x0 = xv[2 * kk], x1 = xv[2 * kk + 1];
            frag_ab A;
            A[0] = f2bf(x0.x); A[1] = f2bf(x0.y); A[2] = f2bf(x0.z); A[3] = f2bf(x0.w);
            A[4] = f2bf(x1.x); A[5] = f2bf(x1.y); A[6] = f2bf(x1.z); A[7] = f2bf(x1.w);
#pragma unroll
            for (int nt = 0; nt < 4; ++nt)
                acc[nt] = __builtin_amdgcn_mfma_f32_16x16x32_bf16(A, Bf[kk][nt],
                                                                  acc[nt], 0, 0, 0);
        }
#pragma unroll
        for (int nt = 0; nt < 4; ++nt) {
#pragma unroll
            for (int r = 0; r < 4; ++r) {
                const int node = node_base + quad * 4 + r;
                if (node < n_nodes)
                    h[(size_t)node * D_OUT + nt * 16 + m] =
                        (unsigned short)f2bf(acc[nt][r]);
            }
        }
    }
}

// ---------------------------------------------------------------------------
// Fused bucket-build + gather, EXACT (no downstream overflow kernel).
// Block = (bin, slice of 64 nodes). ovfA records feed the same lbuck path
// (deg + contribution); entries beyond CAP stream into facc (LDS f32,
// on-CU atomics, zero work when empty). Gather: wave per node, quarter-wave
// per bucket entry, 4-way-unrolled uint2 h loads for MLP, shfl_xor reduce,
// facc fold, fused mean. Each block owns its 64 out rows -> no global atomics.
// ---------------------------------------------------------------------------
__global__ __launch_bounds__(FAT_THREADS)
void bin_gather_kernel(const unsigned* __restrict__ scratch,
                       const int* __restrict__ cursor,
                       const uint2* __restrict__ h64,
                       int* __restrict__ deg,
                       const unsigned* __restrict__ ovfA_list,
                       const int* __restrict__ ovfA_cnt, int ovfA_cap,
                       float* __restrict__ out, int n_nodes) {
    __shared__ int ldeg[64];
    __shared__ unsigned short lbuck[64 * CAP];   // 8 KB
    __shared__ float facc[64 * D_OUT];           // 16 KB overflow accumulator
    const int g     = (int)blockIdx.x;
    const int bin   = g >> SPLIT_SHIFT;
    const int slice = g & (SPLIT - 1);
    const int node0 = (bin << BIN_SHIFT) + (slice << 6);
    const int tid   = (int)threadIdx.x;

    int cnt = cursor[bin * 16]; if (cnt > BIN_CAP) cnt = BIN_CAP;

    if (tid < 64) ldeg[tid] = 0;
    for (int i = tid; i < 64 * D_OUT; i += FAT_THREADS) facc[i] = 0.f;
    __syncthreads();

    // scan the bin's records, keep rows in [slice*64, slice*64+64)
    for (int i = tid; i < cnt; i += FAT_THREADS) {
        const unsigned rec = scratch[(size_t)bin * BIN_CAP + i];
        const int rl = (int)(rec & 255u);
        if ((rl >> 6) == slice) {
            const int r6 = rl & 63;
            const int s = atomicAdd(&ldeg[r6], 1);
            if (s < CAP) lbuck[(r6 << 6) + s] = (unsigned short)(rec >> 8);
            else         facc_accum(facc, h64, r6, (int)(rec >> 8));
        }
    }
    // pass1-overflow edges: same path (deg + contribution), fast path = 0 work
    int cA = *ovfA_cnt; if (cA > ovfA_cap) cA = ovfA_cap;
    if (cA > 0) {
        const int gslice = node0 >> 6;
        for (int i = tid; i < cA; i += FAT_THREADS) {
            const unsigned rec = ovfA_list[i];
            const int r = (int)(rec & 0xFFFFu);
            if ((r >> 6) == gslice) {
                const int r6 = r & 63;
                const int c = (int)(rec >> 16);
                const int s = atomicAdd(&ldeg[r6], 1);
                if (s < CAP) lbuck[(r6 << 6) + s] = (unsigned short)c;
                else         facc_accum(facc, h64, r6, c);
            }
        }
    }
    __syncthreads();

    if (tid < 64 && node0 + tid < n_nodes) deg[node0 + tid] = ldeg[tid];

    // gather straight from LDS buckets
    const int lane = tid & 63;
    const int q = lane >> 4;
    const int j = lane & 15;
    const int w = tid >> 6;   // wave 0..7

    for (int r6 = w; r6 < 64; r6 += 8) {
        const int node = node0 + r6;
        if (node >= n_nodes) continue;
        const int d = ldeg[r6];
        const int dc = d < CAP ? d : CAP;
        const int ngr = (dc + 3) >> 2;
        const unsigned short* brow = &lbuck[r6 << 6];

        float a0 = 0.f, a1 = 0.f, a2 = 0.f, a3 = 0.f;
        float b0 = 0.f, b1 = 0.f, b2 = 0.f, b3 = 0.f;
        int g2 = 0;
        for (; g2 + 4 <= ngr; g2 += 4) {          // 4 loads in flight (MLP)
            const int i0 = (int)brow[4 * g2 + q];
            const int i1 = (int)brow[4 * g2 + 4 + q];
            const int i2 = (int)brow[4 * g2 + 8 + q];
            const int i3 = (int)brow[4 * g2 + 12 + q];
            uint2 w0 = h64[(size_t)i0 * 16 + j];
            uint2 w1 = h64[(size_t)i1 * 16 + j];
            uint2 w2 = h64[(size_t)i2 * 16 + j];
            uint2 w3 = h64[(size_t)i3 * 16 + j];
            if (4 * g2 + 12 + q >= dc) { w3.x = 0u; w3.y = 0u; }
            a0 += bflo(w0.x); a1 += bfhi(w0.x); a2 += bflo(w0.y); a3 += bfhi(w0.y);
            b0 += bflo(w1.x); b1 += bfhi(w1.x); b2 += bflo(w1.y); b3 += bfhi(w1.y);
            a0 += bflo(w2.x); a1 += bfhi(w2.x); a2 += bflo(w2.y); a3 += bfhi(w2.y);
            b0 += bflo(w3.x); b1 += bfhi(w3.x); b2 += bflo(w3.y); b3 += bfhi(w3.y);
        }
        for (; g2 + 2 <= ngr; g2 += 2) {
            const int iA = (int)brow[4 * g2 + q];
            const int iB = (int)brow[4 * g2 + 4 + q];
            uint2 wA = h64[(size_t)iA * 16 + j];
            uint2 wB = h64[(size_t)iB * 16 + j];
            if (4 * g2 + q >= dc)     { wA.x = 0u; wA.y = 0u; }
            if (4 * g2 + 4 + q >= dc) { wB.x = 0u; wB.y = 0u; }
            a0 += bflo(wA.x); a1 += bfhi(wA.x); a2 += bflo(wA.y); a3 += bfhi(wA.y);
            b0 += bflo(wB.x); b1 += bfhi(wB.x); b2 += bflo(wB.y); b3 += bfhi(wB.y);
        }
        for (; g2 < ngr; ++g2) {
            const int iA = (int)brow[4 * g2 + q];
            uint2 wA = h64[(size_t)iA * 16 + j];
            if (4 * g2 + q >= dc) { wA.x = 0u; wA.y = 0u; }
            a0 += bflo(wA.x); a1 += bfhi(wA.x); a2 += bflo(wA.y); a3 += bfhi(wA.y);
        }
        a0 += b0; a1 += b1; a2 += b2; a3 += b3;
        a0 += __shfl_xor(a0, 16); a0 += __shfl_xor(a0, 32);
        a1 += __shfl_xor(a1, 16); a1 += __shfl_xor(a1, 32);
        a2 += __shfl_xor(a2, 16); a2 += __shfl_xor(a2, 32);
        a3 += __shfl_xor(a3, 16); a3 += __shfl_xor(a3, 32);
        if (q == 0) {
            const float* fa = &facc[(r6 << 6) + j * 4];
            const float inv = 1.0f / fmaxf((float)d, 1.0f);
            float4 o;
            o.x = (a0 + fa[0]) * inv; o.y = (a1 + fa[1]) * inv;
            o.z = (a2 + fa[2]) * inv; o.w = (a3 + fa[3]) * inv;
            *(float4*)(out + (size_t)node * D_OUT + j * 4) = o;
        }
    }
}

// ---------------------------------------------------------------------------
// Last-resort path (ws too small or n_nodes > 65536): fp32 h + atomic scatter.
// ---------------------------------------------------------------------------
__global__ void proj_only_kernel(const float* __restrict__ x,
                                 const float* __restrict__ W,
                                 const float* __restrict__ bvec,
                                 float* __restrict__ h, int n_nodes) {
    const int lane = (int)threadIdx.x & 63;
    const int wave = (int)((blockIdx.x * blockDim.x + threadIdx.x) >> 6);
    const int nwaves = (int)((gridDim.x * blockDim.x) >> 6);
    const float bias = bvec[lane];
    for (int node = wave; node < n_nodes; node += nwaves) {
        const float* xr = &x[(size_t)node * D_IN];
        float acc = bias;
#pragma unroll
        for (int k = 0; k < D_IN; ++k) acc += xr[k] * W[lane * D_IN + k];
        h[(size_t)node * D_OUT + lane] = acc;
    }
}

__global__ void scatter_kernel(const float* __restrict__ h,
                               const int* __restrict__ row,
                               const int* __restrict__ col,
                               float* __restrict__ out,
                               int* __restrict__ deg,
                               long long n_tasks) {
    long long t = (long long)blockIdx.x * blockDim.x + threadIdx.x;
    const long long stride = (long long)gridDim.x * blockDim.x;
    for (; t < n_tasks; t += stride) {
        const int e = (int)(t >> 6);
        const int c = (int)(t & 63);
        atomicAdd(&out[(size_t)row[e] * D_OUT + c], h[(size_t)col[e] * D_OUT + c]);
        if (c == 0) atomicAdd(&deg[row[e]], 1);
    }
}

__global__ void div_kernel(float* __restrict__ out,
                           const int* __restrict__ deg, int n_total) {
    int t = blockIdx.x * blockDim.x + threadIdx.x;
    if (t < n_total) {
        out[t] *= 1.0f / fmaxf((float)deg[t >> 6], 1.0f);
    }
}

extern "C" void kernel_launch(void* const* d_in, const int* in_sizes, int n_in,
                              void* d_out, int out_size, void* d_ws, size_t ws_size,
                              hipStream_t stream) {
    const float* x   = (const float*)d_in[0];
    const float* W   = (const float*)d_in[1];
    const float* b   = (const float*)d_in[2];
    const int*   row = (const int*)d_in[3];
    const int*   col = (const int*)d_in[4];
    float* out = (float*)d_out;

    const int n_nodes = in_sizes[0] / D_IN;
    const int n_edges = in_sizes[3];
    const int n_bins  = (n_nodes + 255) >> BIN_SHIFT;

    // Workspace: h(bf16) | deg | [ovfA_cnt pad 256B] | cursor(padded)
    //            | ovfA_list | scratch
    char* p = (char*)d_ws;
    unsigned short* h = (unsigned short*)p;
    p += (size_t)n_nodes * D_OUT * sizeof(unsigned short);
    int* deg = (int*)p;            p += (size_t)n_nodes * sizeof(int);
    int* ovf_cnts = (int*)p;       p += 256;                       // [0]=A
    int* cursor = (int*)p;         p += (size_t)MAX_BINS * 16 * sizeof(int);
    unsigned* ovfA_list = (unsigned*)p;  p += (size_t)n_edges * sizeof(unsigned);
    unsigned* scratch = (unsigned*)p;
    p += (size_t)n_bins * BIN_CAP * sizeof(unsigned);
    const size_t needed = (size_t)(p - (char*)d_ws);

    if (ws_size >= needed && n_nodes <= MAX_USHORT_NODES) {
        // zero: ovfA counter + padded cursor (contiguous)
        hipMemsetAsync(ovf_cnts, 0, 256 + (size_t)MAX_BINS * 16 * sizeof(int),
                       stream);

        // 1) projection || binpass1 (independent; complementary pipes)
        const int ntiles = (n_nodes + 15) / 16;
        int proj_blocks = (ntiles + 15) / 16;     // 8 waves/block, 2 tiles/wave
        if (proj_blocks < 1) proj_blocks = 1;
        proj_bin1_kernel<<<P1_BLOCKS + proj_blocks, FAT_THREADS, 0, stream>>>(
            x, W, b, h, row, col, scratch, cursor, &ovf_cnts[0], ovfA_list,
            n_edges, n_nodes, n_edges, n_bins);

        // 2) fused bucket-build + gather, exact (no downstream kernel)
        bin_gather_kernel<<<n_bins * SPLIT, FAT_THREADS, 0, stream>>>(
            scratch, cursor, (const uint2*)h, deg, ovfA_list, &ovf_cnts[0],
            n_edges, out, n_nodes);
    } else {
        // last resort: fp32 h + atomic scatter
        float* hf = (float*)d_ws;
        int* degf = (int*)((char*)d_ws + (size_t)n_nodes * D_OUT * sizeof(float));
        hipMemsetAsync(out, 0, (size_t)out_size * sizeof(float), stream);
        hipMemsetAsync(degf, 0, (size_t)n_nodes * sizeof(int), stream);
        proj_only_kernel<<<1024, 256, 0, stream>>>(x, W, b, hf, n_nodes);
        const long long n_tasks = (long long)n_edges * D_OUT;
        scatter_kernel<<<16384, 256, 0, stream>>>(hf, row, col, out, degf, n_tasks);
        const int n_total = n_nodes * D_OUT;
        div_kernel<<<(n_total + 255) / 256, 256, 0, stream>>>(out, degf, n_total);
    }
}